// Round 6
// baseline (182.442 us; speedup 1.0000x reference)
//
#include <hip/hip_runtime.h>
#include <hip/hip_bf16.h>

typedef __attribute__((ext_vector_type(8))) short bf16x8;
typedef __attribute__((ext_vector_type(4))) float f32x4;

#define CO    256
#define CI    2048
#define BATCH 8
#define HW    1024
#define NTOT  (BATCH * CI * HW)

#define BK    64          // k per step (2 MFMA k-halves)
#define BHW   16          // hw per block
#define LDA   64          // shorts per As row (128B, no pad; XOR-swizzled slots)

static __device__ __forceinline__ float fabs4max(const float4 v) {
  return fmaxf(fmaxf(fabsf(v.x), fabsf(v.y)), fmaxf(fabsf(v.z), fabsf(v.w)));
}

static __device__ __forceinline__ short f32_to_bf16_bits(float f) {
  return (short)(__float_as_uint(f) >> 16);
}

static __device__ __forceinline__ short quant1(float v, float inv_s) {
  return f32_to_bf16_bits(fminf(fmaxf(rintf(v * inv_s), -128.0f), 127.0f));
}

// ---- K1: global abs-max of x (4-way ILP) ----------------------------------
__global__ __launch_bounds__(256) void absmax_kernel(const float* __restrict__ x,
                                                     unsigned int* __restrict__ absbits,
                                                     long long n4) {
  long long i = (long long)blockIdx.x * blockDim.x + threadIdx.x;
  const long long stride = (long long)gridDim.x * blockDim.x;
  const float4* x4 = (const float4*)x;
  float m0 = 0.0f, m1 = 0.0f, m2 = 0.0f, m3 = 0.0f;
  for (; i + 3 * stride < n4; i += 4 * stride) {
    m0 = fmaxf(m0, fabs4max(x4[i]));
    m1 = fmaxf(m1, fabs4max(x4[i + stride]));
    m2 = fmaxf(m2, fabs4max(x4[i + 2 * stride]));
    m3 = fmaxf(m3, fabs4max(x4[i + 3 * stride]));
  }
  for (; i < n4; i += stride) m0 = fmaxf(m0, fabs4max(x4[i]));
  float m = fmaxf(fmaxf(m0, m1), fmaxf(m2, m3));
#pragma unroll
  for (int off = 32; off; off >>= 1) m = fmaxf(m, __shfl_xor(m, off));
  __shared__ float red[4];
  if ((threadIdx.x & 63) == 0) red[threadIdx.x >> 6] = m;
  __syncthreads();
  if (threadIdx.x == 0) {
    m = fmaxf(fmaxf(red[0], red[1]), fmaxf(red[2], red[3]));
    atomicMax(absbits, __float_as_uint(m));   // all vals >= 0: bit order = uint order
  }
}

// ---- K2: per-output-channel weight quant + alpha/beta ---------------------
__global__ __launch_bounds__(256) void wquant_kernel(const float* __restrict__ w,
                                                     const float* __restrict__ bias,
                                                     const unsigned int* __restrict__ absbits,
                                                     short* __restrict__ qw,
                                                     float* __restrict__ alpha,
                                                     float* __restrict__ beta) {
  const int co = blockIdx.x;
  const int t = threadIdx.x;
  const float* row = w + (size_t)co * CI;
  const float4 v0 = ((const float4*)row)[t * 2];
  const float4 v1 = ((const float4*)row)[t * 2 + 1];
  float m = fmaxf(fabs4max(v0), fabs4max(v1));
#pragma unroll
  for (int off = 32; off; off >>= 1) m = fmaxf(m, __shfl_xor(m, off));
  __shared__ float red[4];
  __shared__ float s_sw;
  if ((t & 63) == 0) red[t >> 6] = m;
  __syncthreads();
  if (t == 0) {
    const float mm = fmaxf(fmaxf(red[0], red[1]), fmaxf(red[2], red[3]));
    s_sw = fmaxf(mm, 1e-8f) / 127.0f;
  }
  __syncthreads();
  const float sw = s_sw;

  const float vals[8] = {v0.x, v0.y, v0.z, v0.w, v1.x, v1.y, v1.z, v1.w};
  bf16x8 qv;
#pragma unroll
  for (int j = 0; j < 8; ++j) {
    const float q = fminf(fmaxf(rintf(vals[j] / sw), -128.0f), 127.0f);
    qv[j] = f32_to_bf16_bits(q);
  }
  *(bf16x8*)(qw + (size_t)co * CI + t * 8) = qv;

  if (t == 0) {
    const float sa = fmaxf(__uint_as_float(*absbits), 1e-8f) / 127.0f;
    const float a = sa * sw;
    alpha[co] = a;
    beta[co] = rintf(bias[co] / a) * a;
  }
}

// ---- K3: swapped-operand bf16 MFMA GEMM -----------------------------------
// D[r=hw][c=co]; block = co 256 x hw 16, BK=64; 256 thr = 4 waves (wave=co 64).
// grid = 8 b * 64 hw-tiles = 512 blocks = 2 independent blocks/CU.
// LDS: As[256][64] qw tile, Bs[16][64] qx tile, 16B slots XOR-swizzled by row&7.
__global__ __launch_bounds__(256) void gemm_kernel(const float* __restrict__ x,
                                                   const short* __restrict__ qw,
                                                   const float* __restrict__ alpha,
                                                   const float* __restrict__ beta,
                                                   const unsigned int* __restrict__ absbits,
                                                   float* __restrict__ out) {
  __shared__ short As[CO * LDA];     // 32 KB
  __shared__ short Bs[BHW * LDA];    // 2 KB

  const int hwt = blockIdx.x & 63;
  const int b = blockIdx.x >> 6;
  const int hw0 = hwt * BHW;

  const float sa = fmaxf(__uint_as_float(*absbits), 1e-8f) / 127.0f;
  const float inv_sa = 1.0f / sa;

  const int t = threadIdx.x;
  const int lane = t & 63;
  const int w = t >> 6;              // 0..3
  const int wco = w * 64;
  const int lr = lane & 15;
  const int kg = lane >> 4;          // 0..3
  const int rsw = lr & 7;            // read-side swizzle key

  // staging roles
  const int arow = t;                // 0..255: each thread stages one full A row
  const int asw = arow & 7;          // write-side swizzle key
  const int bk = t >> 2;             // 0..63 (k)
  const int bhw = (t & 3) * 4;       // 0,4,8,12 (hw quad)

  const short* ap0 = qw + (size_t)arow * CI;
  const float* xp0 = x + ((size_t)b * CI + bk) * HW + hw0 + bhw;

  f32x4 acc[4] = {};

  bf16x8 av[8];
  float4 xv;
#pragma unroll
  for (int s = 0; s < 8; ++s) av[s] = *(const bf16x8*)(ap0 + s * 8);
  xv = *(const float4*)(xp0);

  for (int k0 = 0; k0 < CI; k0 += BK) {
    __syncthreads();   // prior compute done before overwriting LDS
#pragma unroll
    for (int s = 0; s < 8; ++s)
      *(bf16x8*)&As[arow * LDA + ((s ^ asw) << 3)] = av[s];
    {
      const int sl = bk >> 3, kq = bk & 7;
      const float f[4] = {xv.x, xv.y, xv.z, xv.w};
#pragma unroll
      for (int j = 0; j < 4; ++j) {
        const int row = bhw + j;
        Bs[row * LDA + ((sl ^ (row & 7)) << 3) + kq] = quant1(f[j], inv_sa);
      }
    }

    // prefetch next K-tile (wrapped on last iter; values discarded)
    const int kn = (k0 + BK) & (CI - 1);
#pragma unroll
    for (int s = 0; s < 8; ++s) av[s] = *(const bf16x8*)(ap0 + kn + s * 8);
    xv = *(const float4*)(xp0 + (size_t)kn * HW);

    __syncthreads();

#pragma unroll
    for (int h = 0; h < 2; ++h) {
      const int ph = ((h * 4 + kg) ^ rsw) << 3;   // swizzled slot byte-offset/2
      const bf16x8 aF = *(const bf16x8*)&Bs[lr * LDA + ph];
#pragma unroll
      for (int n = 0; n < 4; ++n) {
        const bf16x8 bF = *(const bf16x8*)&As[(wco + n * 16 + lr) * LDA + ph];
        acc[n] = __builtin_amdgcn_mfma_f32_16x16x32_bf16(aF, bF, acc[n], 0, 0, 0);
      }
    }
  }

  // epilogue: D row = hw = kg*4 + reg (4 consecutive hw), D col = co
  const int hwo = hw0 + kg * 4;
#pragma unroll
  for (int n = 0; n < 4; ++n) {
    const int co = wco + n * 16 + lr;
    const float af = alpha[co];
    const float bf = beta[co];
    float4 v;
    v.x = acc[n][0] * af + bf;
    v.y = acc[n][1] * af + bf;
    v.z = acc[n][2] * af + bf;
    v.w = acc[n][3] * af + bf;
    *(float4*)(out + ((size_t)(b * CO + co)) * HW + hwo) = v;
  }
}

extern "C" void kernel_launch(void* const* d_in, const int* in_sizes, int n_in,
                              void* d_out, int out_size, void* d_ws, size_t ws_size,
                              hipStream_t stream) {
  const float* x    = (const float*)d_in[0];
  const float* wgt  = (const float*)d_in[1];
  const float* bias = (const float*)d_in[2];
  float* out = (float*)d_out;

  unsigned int* absbits = (unsigned int*)d_ws;
  short* qw    = (short*)((char*)d_ws + 256);
  float* alpha = (float*)((char*)d_ws + 256 + (size_t)CO * CI * 2);
  float* beta  = alpha + CO;

  hipMemsetAsync(d_ws, 0, 4, stream);
  absmax_kernel<<<2048, 256, 0, stream>>>(x, absbits, (long long)(NTOT / 4));
  wquant_kernel<<<CO, 256, 0, stream>>>(wgt, bias, absbits, qw, alpha, beta);
  gemm_kernel<<<BATCH * 64, 256, 0, stream>>>(x, qw, alpha, beta, absbits, out);
}

// Round 7
// 144.811 us; speedup vs baseline: 1.2599x; 1.2599x over previous
//
#include <hip/hip_runtime.h>
#include <hip/hip_bf16.h>

typedef __attribute__((ext_vector_type(8))) short bf16x8;
typedef __attribute__((ext_vector_type(4))) float f32x4;

#define CO    256
#define CI    2048
#define BATCH 8
#define HW    1024
#define NTOT  (BATCH * CI * HW)

#define BM    128         // co per block (2 co-tiles)
#define BHW   32          // hw per block
#define BK    64          // k per step
#define LDA   72          // padded row stride in shorts (144B = 36 dwords -> row bank base rotates by 4)

static __device__ __forceinline__ float fabs4max(const float4 v) {
  return fmaxf(fmaxf(fabsf(v.x), fabsf(v.y)), fmaxf(fabsf(v.z), fabsf(v.w)));
}

static __device__ __forceinline__ short f32_to_bf16_bits(float f) {
  return (short)(__float_as_uint(f) >> 16);
}

static __device__ __forceinline__ short quant1(float v, float inv_s) {
  return f32_to_bf16_bits(fminf(fmaxf(rintf(v * inv_s), -128.0f), 127.0f));
}

// ---- K1: global abs-max of x (4-way ILP) ----------------------------------
__global__ __launch_bounds__(256) void absmax_kernel(const float* __restrict__ x,
                                                     unsigned int* __restrict__ absbits,
                                                     long long n4) {
  long long i = (long long)blockIdx.x * blockDim.x + threadIdx.x;
  const long long stride = (long long)gridDim.x * blockDim.x;
  const float4* x4 = (const float4*)x;
  float m0 = 0.0f, m1 = 0.0f, m2 = 0.0f, m3 = 0.0f;
  for (; i + 3 * stride < n4; i += 4 * stride) {
    m0 = fmaxf(m0, fabs4max(x4[i]));
    m1 = fmaxf(m1, fabs4max(x4[i + stride]));
    m2 = fmaxf(m2, fabs4max(x4[i + 2 * stride]));
    m3 = fmaxf(m3, fabs4max(x4[i + 3 * stride]));
  }
  for (; i < n4; i += stride) m0 = fmaxf(m0, fabs4max(x4[i]));
  float m = fmaxf(fmaxf(m0, m1), fmaxf(m2, m3));
#pragma unroll
  for (int off = 32; off; off >>= 1) m = fmaxf(m, __shfl_xor(m, off));
  __shared__ float red[4];
  if ((threadIdx.x & 63) == 0) red[threadIdx.x >> 6] = m;
  __syncthreads();
  if (threadIdx.x == 0) {
    m = fmaxf(fmaxf(red[0], red[1]), fmaxf(red[2], red[3]));
    atomicMax(absbits, __float_as_uint(m));   // vals >= 0: bit order = uint order
  }
}

// ---- K2: per-output-channel weight quant + alpha/beta ---------------------
__global__ __launch_bounds__(256) void wquant_kernel(const float* __restrict__ w,
                                                     const float* __restrict__ bias,
                                                     const unsigned int* __restrict__ absbits,
                                                     short* __restrict__ qw,
                                                     float* __restrict__ alpha,
                                                     float* __restrict__ beta) {
  const int co = blockIdx.x;
  const int t = threadIdx.x;
  const float* row = w + (size_t)co * CI;
  const float4 v0 = ((const float4*)row)[t * 2];
  const float4 v1 = ((const float4*)row)[t * 2 + 1];
  float m = fmaxf(fabs4max(v0), fabs4max(v1));
#pragma unroll
  for (int off = 32; off; off >>= 1) m = fmaxf(m, __shfl_xor(m, off));
  __shared__ float red[4];
  __shared__ float s_sw;
  if ((t & 63) == 0) red[t >> 6] = m;
  __syncthreads();
  if (t == 0) {
    const float mm = fmaxf(fmaxf(red[0], red[1]), fmaxf(red[2], red[3]));
    s_sw = fmaxf(mm, 1e-8f) / 127.0f;
  }
  __syncthreads();
  const float sw = s_sw;

  const float vals[8] = {v0.x, v0.y, v0.z, v0.w, v1.x, v1.y, v1.z, v1.w};
  bf16x8 qv;
#pragma unroll
  for (int j = 0; j < 8; ++j) {
    const float q = fminf(fmaxf(rintf(vals[j] / sw), -128.0f), 127.0f);
    qv[j] = f32_to_bf16_bits(q);
  }
  *(bf16x8*)(qw + (size_t)co * CI + t * 8) = qv;

  if (t == 0) {
    const float sa = fmaxf(__uint_as_float(*absbits), 1e-8f) / 127.0f;
    const float a = sa * sw;
    alpha[co] = a;
    beta[co] = rintf(bias[co] / a) * a;
  }
}

// ---- K3: swapped-operand bf16 MFMA GEMM -----------------------------------
// D[r=hw][c=co]; block = 128co x 32hw, BK=64; 512 thr = 8 waves (4 wco x 2 whw).
// grid = 2 co-tiles * 32 hw-tiles * 8 b = 512 blocks = 2 blocks/CU (16 waves/CU).
// A staging COALESCED: 8 lanes x 16B = one full 128B row-chunk (full L2 lines).
// LDS rows padded to 72 shorts: frag reads 2-way (free), stage writes uniform.
__global__ __launch_bounds__(512) void gemm_kernel(const float* __restrict__ x,
                                                   const short* __restrict__ qw,
                                                   const float* __restrict__ alpha,
                                                   const float* __restrict__ beta,
                                                   const unsigned int* __restrict__ absbits,
                                                   float* __restrict__ out) {
  __shared__ short As[BM * LDA];    // 18 KB
  __shared__ short Bs[BHW * LDA];   // 4.6 KB

  const int cot = blockIdx.x & 1;
  const int hwt = (blockIdx.x >> 1) & 31;
  const int b = blockIdx.x >> 6;
  const int co0 = cot * BM;
  const int hw0 = hwt * BHW;

  const float sa = fmaxf(__uint_as_float(*absbits), 1e-8f) / 127.0f;
  const float inv_sa = 1.0f / sa;

  const int t = threadIdx.x;
  const int lane = t & 63;
  const int w = t >> 6;              // 0..7
  const int wco = (w & 3) * 32;      // co group (32 wide)
  const int whw = (w >> 2) * 16;     // hw group (16 wide)
  const int lr = lane & 15;
  const int kg = lane >> 4;          // 0..3

  // staging roles (coalesced: 8 lanes cover one 128B row-chunk)
  const int arow = t >> 3;           // 0..63  (pass 1 adds +64)
  const int aslot = t & 7;           // 16B slot within the 128B row-chunk
  const int bk = t >> 3;             // 0..63 (k)
  const int bhw0 = (t & 7) * 4;      // hw quad

  const short* ap0 = qw + (size_t)(co0 + arow) * CI + aslot * 8;
  const short* ap1 = ap0 + (size_t)64 * CI;
  const float* xp0 = x + ((size_t)b * CI + bk) * HW + hw0 + bhw0;

  f32x4 acc[2] = {};

  bf16x8 av0 = *(const bf16x8*)(ap0);
  bf16x8 av1 = *(const bf16x8*)(ap1);
  float4 xv = *(const float4*)(xp0);

  for (int k0 = 0; k0 < CI; k0 += BK) {
    __syncthreads();   // prior compute done before overwriting LDS
    *(bf16x8*)&As[arow * LDA + aslot * 8] = av0;
    *(bf16x8*)&As[(arow + 64) * LDA + aslot * 8] = av1;
    {
      const float f[4] = {xv.x, xv.y, xv.z, xv.w};
#pragma unroll
      for (int j = 0; j < 4; ++j)
        Bs[(bhw0 + j) * LDA + bk] = quant1(f[j], inv_sa);
    }

    // prefetch next K-tile (wrapped on last iter; values discarded)
    const int kn = (k0 + BK) & (CI - 1);
    av0 = *(const bf16x8*)(ap0 + kn);
    av1 = *(const bf16x8*)(ap1 + kn);
    xv = *(const float4*)(xp0 + (size_t)kn * HW);

    __syncthreads();

#pragma unroll
    for (int h = 0; h < 2; ++h) {
      const int off = (h * 4 + kg) * 8;
      const bf16x8 aF = *(const bf16x8*)&Bs[(whw + lr) * LDA + off];
#pragma unroll
      for (int n = 0; n < 2; ++n) {
        const bf16x8 bF = *(const bf16x8*)&As[(wco + n * 16 + lr) * LDA + off];
        acc[n] = __builtin_amdgcn_mfma_f32_16x16x32_bf16(aF, bF, acc[n], 0, 0, 0);
      }
    }
  }

  // epilogue: D row = hw = kg*4 + reg (4 consecutive hw per lane), D col = co
  const int hwo = hw0 + whw + kg * 4;
#pragma unroll
  for (int n = 0; n < 2; ++n) {
    const int co = co0 + wco + n * 16 + lr;
    const float af = alpha[co];
    const float bf = beta[co];
    float4 v;
    v.x = acc[n][0] * af + bf;
    v.y = acc[n][1] * af + bf;
    v.z = acc[n][2] * af + bf;
    v.w = acc[n][3] * af + bf;
    *(float4*)(out + ((size_t)(b * CO + co)) * HW + hwo) = v;
  }
}

extern "C" void kernel_launch(void* const* d_in, const int* in_sizes, int n_in,
                              void* d_out, int out_size, void* d_ws, size_t ws_size,
                              hipStream_t stream) {
  const float* x    = (const float*)d_in[0];
  const float* wgt  = (const float*)d_in[1];
  const float* bias = (const float*)d_in[2];
  float* out = (float*)d_out;

  unsigned int* absbits = (unsigned int*)d_ws;
  short* qw    = (short*)((char*)d_ws + 256);
  float* alpha = (float*)((char*)d_ws + 256 + (size_t)CO * CI * 2);
  float* beta  = alpha + CO;

  hipMemsetAsync(d_ws, 0, 4, stream);
  absmax_kernel<<<2048, 256, 0, stream>>>(x, absbits, (long long)(NTOT / 4));
  wquant_kernel<<<CO, 256, 0, stream>>>(wgt, bias, absbits, qw, alpha, beta);
  gemm_kernel<<<2 * 32 * BATCH, 512, 0, stream>>>(x, qw, alpha, beta, absbits, out);
}

// Round 9
// 144.236 us; speedup vs baseline: 1.2649x; 1.0040x over previous
//
#include <hip/hip_runtime.h>
#include <hip/hip_bf16.h>

typedef __attribute__((ext_vector_type(8))) short bf16x8;
typedef __attribute__((ext_vector_type(4))) float f32x4;

#define CO    256
#define CI    2048
#define BATCH 8
#define HW    1024
#define NTOT  (BATCH * CI * HW)

#define BM    128         // co per block (2 co-tiles)
#define BHW   32          // hw per block
#define BK    64          // k per step
#define LDA   72          // padded row stride in shorts (144B -> row bank base rotates)

static __device__ __forceinline__ float fabs4max(const float4 v) {
  return fmaxf(fmaxf(fabsf(v.x), fabsf(v.y)), fmaxf(fabsf(v.z), fabsf(v.w)));
}

static __device__ __forceinline__ short f32_to_bf16_bits(float f) {
  return (short)(__float_as_uint(f) >> 16);
}

static __device__ __forceinline__ short quant1(float v, float inv_s) {
  return f32_to_bf16_bits(fminf(fmaxf(rintf(v * inv_s), -128.0f), 127.0f));
}

// ---- K1: global abs-max of x (4-way ILP) ----------------------------------
__global__ __launch_bounds__(256) void absmax_kernel(const float* __restrict__ x,
                                                     unsigned int* __restrict__ absbits,
                                                     long long n4) {
  long long i = (long long)blockIdx.x * blockDim.x + threadIdx.x;
  const long long stride = (long long)gridDim.x * blockDim.x;
  const float4* x4 = (const float4*)x;
  float m0 = 0.0f, m1 = 0.0f, m2 = 0.0f, m3 = 0.0f;
  for (; i + 3 * stride < n4; i += 4 * stride) {
    m0 = fmaxf(m0, fabs4max(x4[i]));
    m1 = fmaxf(m1, fabs4max(x4[i + stride]));
    m2 = fmaxf(m2, fabs4max(x4[i + 2 * stride]));
    m3 = fmaxf(m3, fabs4max(x4[i + 3 * stride]));
  }
  for (; i < n4; i += stride) m0 = fmaxf(m0, fabs4max(x4[i]));
  float m = fmaxf(fmaxf(m0, m1), fmaxf(m2, m3));
#pragma unroll
  for (int off = 32; off; off >>= 1) m = fmaxf(m, __shfl_xor(m, off));
  __shared__ float red[4];
  if ((threadIdx.x & 63) == 0) red[threadIdx.x >> 6] = m;
  __syncthreads();
  if (threadIdx.x == 0) {
    m = fmaxf(fmaxf(red[0], red[1]), fmaxf(red[2], red[3]));
    atomicMax(absbits, __float_as_uint(m));   // vals >= 0: bit order = uint order
  }
}

// ---- K2: per-output-channel weight quant + alpha/beta ---------------------
__global__ __launch_bounds__(256) void wquant_kernel(const float* __restrict__ w,
                                                     const float* __restrict__ bias,
                                                     const unsigned int* __restrict__ absbits,
                                                     short* __restrict__ qw,
                                                     float* __restrict__ alpha,
                                                     float* __restrict__ beta) {
  const int co = blockIdx.x;
  const int t = threadIdx.x;
  const float* row = w + (size_t)co * CI;
  const float4 v0 = ((const float4*)row)[t * 2];
  const float4 v1 = ((const float4*)row)[t * 2 + 1];
  float m = fmaxf(fabs4max(v0), fabs4max(v1));
#pragma unroll
  for (int off = 32; off; off >>= 1) m = fmaxf(m, __shfl_xor(m, off));
  __shared__ float red[4];
  __shared__ float s_sw;
  if ((t & 63) == 0) red[t >> 6] = m;
  __syncthreads();
  if (t == 0) {
    const float mm = fmaxf(fmaxf(red[0], red[1]), fmaxf(red[2], red[3]));
    s_sw = fmaxf(mm, 1e-8f) / 127.0f;
  }
  __syncthreads();
  const float sw = s_sw;

  const float vals[8] = {v0.x, v0.y, v0.z, v0.w, v1.x, v1.y, v1.z, v1.w};
  bf16x8 qv;
#pragma unroll
  for (int j = 0; j < 8; ++j) {
    const float q = fminf(fmaxf(rintf(vals[j] / sw), -128.0f), 127.0f);
    qv[j] = f32_to_bf16_bits(q);
  }
  *(bf16x8*)(qw + (size_t)co * CI + t * 8) = qv;

  if (t == 0) {
    const float sa = fmaxf(__uint_as_float(*absbits), 1e-8f) / 127.0f;
    const float a = sa * sw;
    alpha[co] = a;
    beta[co] = rintf(bias[co] / a) * a;
  }
}

// ---- K3: swapped-operand bf16 MFMA GEMM -----------------------------------
// D[r=hw][c=co]; block = 128co x 32hw, BK=64; 512 thr = 8 waves (4 wco x 2 whw).
// XCD-PAIRED remap: the two co-tiles of the same (b,hw) tile are placed on the
// SAME XCD (blockIdx differing by 8 -> same bx%8) so the second one reads the
// shared x tile from that XCD's L2 instead of HBM (x streamed from HBM once).
__global__ __launch_bounds__(512) void gemm_kernel(const float* __restrict__ x,
                                                   const short* __restrict__ qw,
                                                   const float* __restrict__ alpha,
                                                   const float* __restrict__ beta,
                                                   const unsigned int* __restrict__ absbits,
                                                   float* __restrict__ out) {
  __shared__ short As[BM * LDA];    // 18 KB
  __shared__ short Bs[BHW * LDA];   // 4.6 KB

  const int bx = blockIdx.x;
  const int T = (bx & 7) | ((bx >> 4) << 3);  // tile id 0..255 (XCD = T&7)
  const int cot = (bx >> 3) & 1;              // co half; twin has same T, same XCD
  const int hwt = T & 31;
  const int b = T >> 5;
  const int co0 = cot * BM;
  const int hw0 = hwt * BHW;

  const float sa = fmaxf(__uint_as_float(*absbits), 1e-8f) / 127.0f;
  const float inv_sa = 1.0f / sa;

  const int t = threadIdx.x;
  const int lane = t & 63;
  const int w = t >> 6;              // 0..7
  const int wco = (w & 3) * 32;      // co group (32 wide)
  const int whw = (w >> 2) * 16;     // hw group (16 wide)
  const int lr = lane & 15;
  const int kg = lane >> 4;          // 0..3

  // staging roles (coalesced: 8 lanes cover one 128B row-chunk)
  const int arow = t >> 3;           // 0..63  (second pass adds +64)
  const int aslot = t & 7;           // 16B slot within the 128B row-chunk
  const int bk = t >> 3;             // 0..63 (k)
  const int bhw0 = (t & 7) * 4;      // hw quad

  const short* ap0 = qw + (size_t)(co0 + arow) * CI + aslot * 8;
  const short* ap1 = ap0 + (size_t)64 * CI;
  const float* xp0 = x + ((size_t)b * CI + bk) * HW + hw0 + bhw0;

  f32x4 acc[2] = {};

  bf16x8 av0 = *(const bf16x8*)(ap0);
  bf16x8 av1 = *(const bf16x8*)(ap1);
  float4 xv = *(const float4*)(xp0);

  for (int k0 = 0; k0 < CI; k0 += BK) {
    __syncthreads();   // prior compute done before overwriting LDS
    *(bf16x8*)&As[arow * LDA + aslot * 8] = av0;
    *(bf16x8*)&As[(arow + 64) * LDA + aslot * 8] = av1;
    {
      const float f[4] = {xv.x, xv.y, xv.z, xv.w};
#pragma unroll
      for (int j = 0; j < 4; ++j)
        Bs[(bhw0 + j) * LDA + bk] = quant1(f[j], inv_sa);
    }

    // prefetch next K-tile (wrapped on last iter; values discarded)
    const int kn = (k0 + BK) & (CI - 1);
    av0 = *(const bf16x8*)(ap0 + kn);
    av1 = *(const bf16x8*)(ap1 + kn);
    xv = *(const float4*)(xp0 + (size_t)kn * HW);

    __syncthreads();

#pragma unroll
    for (int h = 0; h < 2; ++h) {
      const int off = (h * 4 + kg) * 8;
      const bf16x8 aF = *(const bf16x8*)&Bs[(whw + lr) * LDA + off];
#pragma unroll
      for (int n = 0; n < 2; ++n) {
        const bf16x8 bF = *(const bf16x8*)&As[(wco + n * 16 + lr) * LDA + off];
        acc[n] = __builtin_amdgcn_mfma_f32_16x16x32_bf16(aF, bF, acc[n], 0, 0, 0);
      }
    }
  }

  // epilogue: D row = hw = kg*4 + reg (4 consecutive hw per lane), D col = co
  const int hwo = hw0 + whw + kg * 4;
#pragma unroll
  for (int n = 0; n < 2; ++n) {
    const int co = co0 + wco + n * 16 + lr;
    const float af = alpha[co];
    const float bf = beta[co];
    float4 v;
    v.x = acc[n][0] * af + bf;
    v.y = acc[n][1] * af + bf;
    v.z = acc[n][2] * af + bf;
    v.w = acc[n][3] * af + bf;
    *(float4*)(out + ((size_t)(b * CO + co)) * HW + hwo) = v;
  }
}

extern "C" void kernel_launch(void* const* d_in, const int* in_sizes, int n_in,
                              void* d_out, int out_size, void* d_ws, size_t ws_size,
                              hipStream_t stream) {
  const float* x    = (const float*)d_in[0];
  const float* wgt  = (const float*)d_in[1];
  const float* bias = (const float*)d_in[2];
  float* out = (float*)d_out;

  unsigned int* absbits = (unsigned int*)d_ws;
  short* qw    = (short*)((char*)d_ws + 256);
  float* alpha = (float*)((char*)d_ws + 256 + (size_t)CO * CI * 2);
  float* beta  = alpha + CO;

  hipMemsetAsync(d_ws, 0, 4, stream);
  absmax_kernel<<<2048, 256, 0, stream>>>(x, absbits, (long long)(NTOT / 4));
  wquant_kernel<<<CO, 256, 0, stream>>>(wgt, bias, absbits, qw, alpha, beta);
  gemm_kernel<<<2 * 32 * BATCH, 512, 0, stream>>>(x, qw, alpha, beta, absbits, out);
}